// Round 9
// baseline (250.826 us; speedup 1.0000x reference)
//
#include <hip/hip_runtime.h>
#include <hip/hip_bf16.h>

typedef __bf16 bf16;
typedef __attribute__((ext_vector_type(8))) __bf16 bf16x8;
typedef __attribute__((ext_vector_type(4))) float f32x4;

#define LAMBDA_INIT_F 0.3555090675909693f
#define RMS_EPS 1e-5f
// (1/sqrt(128)) * log2(e) : folded into Q so QK^T scores are ready for exp2
#define QSCALE_F 0.1275174053237f

__device__ __forceinline__ void gl_lds16(const bf16* g, bf16* l) {
  __builtin_amdgcn_global_load_lds(
      (const __attribute__((address_space(1))) unsigned int*)g,
      (__attribute__((address_space(3))) unsigned int*)l, 16, 0, 0);
}

// ---------------------------------------------------------------- fused cast f32 -> bf16
__global__ void fused_cast(const float* __restrict__ X, const float* __restrict__ Wq,
                           const float* __restrict__ Wk, const float* __restrict__ Wv,
                           const float* __restrict__ Wo, bf16* __restrict__ out) {
  constexpr int T4 = 3145728;          // 12M elems / 4
  int idx = blockIdx.x * blockDim.x + threadIdx.x;
  int stride = gridDim.x * blockDim.x;
  for (int i = idx; i < T4; i += stride) {
    const float* src;
    int off;
    if (i < 1048576)       { src = X;  off = i; }
    else if (i < 1572864)  { src = Wq; off = i - 1048576; }
    else if (i < 2097152)  { src = Wk; off = i - 1572864; }
    else if (i < 2621440)  { src = Wv; off = i - 2097152; }
    else                   { src = Wo; off = i - 2621440; }
    float4 v = reinterpret_cast<const float4*>(src)[off];
    bf16 o[4];
    o[0] = (bf16)v.x; o[1] = (bf16)v.y; o[2] = (bf16)v.z; o[3] = (bf16)v.w;
    *reinterpret_cast<ushort4*>(&out[(size_t)i * 4]) = *reinterpret_cast<const ushort4*>(o);
  }
}

// ---------------------------------------------------------------- bt-GEMM (global_load_lds, 2-phase dbuf)
// C[m,n] = sum_k A[m,k] * B[n,k]
// MODE 1: f32 row-major out, 2D grid.
// MODE 3: fused QKV epilogue (N=6144), 1D grid 1536 with XCD-rect swizzle:
//         each XCD owns a 12(n)x16(m) block rectangle for L2 locality.
//         region n>>11 == 0 -> Qb bf16 * QSCALE; 1 -> Kb; 2 -> Vt[b,h,e,perm(nseq)]
//         (key 16h+4g+c stored at slot 8g+4h+c for 16B-contiguous attn staging).
template <int MODE, int BM>
__global__ __launch_bounds__(256) void gemm_bt(
    const bf16* __restrict__ A, const bf16* __restrict__ B,
    void* __restrict__ Cv, int M, int N, int K) {
  constexpr int BN = 128, BK = 32;
  constexpr int MF = BM / 32;
  constexpr int CA = BM / 16;
  __shared__ __align__(16) bf16 As[2][BM * BK];
  __shared__ __align__(16) bf16 Bs[2][BN * BK];
  const int tid = threadIdx.x, lane = tid & 63, w = tid >> 6;
  const int l15 = lane & 15, lhi = lane >> 4;
  const int wr = (w >> 1) * (BM / 2), wc = (w & 1) * 64;
  int bm, bn;
  if constexpr (MODE == 3) {
    const int bid = blockIdx.x;
    const int xcd = bid & 7, t = bid >> 3;       // t in 0..191
    const int sx = xcd & 3, sy = xcd >> 2;
    bn = (sx * 12 + t % 12) * 128;               // 48 n-blocks
    bm = (sy * 16 + t / 12) * 128;               // 32 m-blocks
  } else {
    bm = blockIdx.x * BM;
    bn = blockIdx.y * BN;
  }
  const int srow = lane >> 2, scol = (lane & 3) * 8;
  const int NTK = K / BK;
  f32x4 acc[MF][4] = {};

  auto stage = [&](int buf, int k0) {
#pragma unroll
    for (int i = 0; i < CA / 4; ++i) {
      int c = w * (CA / 4) + i;
      gl_lds16(&A[(size_t)(bm + c * 16 + srow) * K + k0 + scol], &As[buf][c * 512]);
    }
#pragma unroll
    for (int i = 0; i < 2; ++i) {
      int c = w * 2 + i;
      gl_lds16(&B[(size_t)(bn + c * 16 + srow) * K + k0 + scol], &Bs[buf][c * 512]);
    }
  };

  stage(0, 0);
  __syncthreads();
  for (int t = 0; t < NTK; ++t) {
    const int buf = t & 1;
    if (t + 1 < NTK) stage(buf ^ 1, (t + 1) * BK);
    bf16x8 af[MF], bfr[4];
#pragma unroll
    for (int mf = 0; mf < MF; ++mf)
      af[mf] = *reinterpret_cast<const bf16x8*>(&As[buf][(wr + mf * 16 + l15) * BK + lhi * 8]);
#pragma unroll
    for (int nf = 0; nf < 4; ++nf)
      bfr[nf] = *reinterpret_cast<const bf16x8*>(&Bs[buf][(wc + nf * 16 + l15) * BK + lhi * 8]);
#pragma unroll
    for (int mf = 0; mf < MF; ++mf)
#pragma unroll
      for (int nf = 0; nf < 4; ++nf)
        acc[mf][nf] = __builtin_amdgcn_mfma_f32_16x16x32_bf16(af[mf], bfr[nf], acc[mf][nf], 0, 0, 0);
    __syncthreads();
  }

#pragma unroll
  for (int mf = 0; mf < MF; ++mf)
#pragma unroll
    for (int nf = 0; nf < 4; ++nf)
#pragma unroll
      for (int r = 0; r < 4; ++r) {
        int m = bm + wr + mf * 16 + lhi * 4 + r;
        int n = bn + wc + nf * 16 + l15;
        if constexpr (MODE == 1) {
          ((float*)Cv)[(size_t)m * N + n] = acc[mf][nf][r];
        } else {
          int reg = n >> 11, nl = n & 2047;
          if (reg == 0) {
            ((bf16*)Cv)[(size_t)m * 2048 + nl] = (bf16)(acc[mf][nf][r] * QSCALE_F);
          } else if (reg == 1) {
            ((bf16*)Cv)[(size_t)(m + 4096) * 2048 + nl] = (bf16)acc[mf][nf][r];
          } else {
            // Vt[b, h, e, perm(nseq)] at Cv + 2*M*2048
            int bb = m >> 11, nq = m & 2047;
            int hh = nl >> 8, e = nl & 255;
            int k5 = nq & 31;
            int slot = (((k5 >> 2) & 3) << 3) | (((k5 >> 4) & 1) << 2) | (k5 & 3);
            int np = (nq & ~31) | slot;
            ((bf16*)Cv)[(size_t)16777216 + ((((size_t)bb * 8 + hh) * 256 + e) << 11) + np] =
                (bf16)acc[mf][nf][r];
          }
        }
      }
}

// ---------------------------------------------------------------- differential flash attention
// grid 256 (1 block/CU, XCD-chunk swizzled), block 1024 = 16 waves:
//   q-group g=w>>1 (16 rows of the 128-row q-tile), stream s=w&1.
// Swapped QK^T -> lane holds 8 P-values of q-row l15. Max-free softmax via exp2
// (Q pre-scaled by SC*log2e); per-lane partial l, reduced in epilogue.
// K in LDS [32][256] with 16B-slot XOR swizzle folded into gl_lds16 source.
// V global layout is slot-permuted (GEMM MODE-3): staging is 16B-contiguous gl_lds16
// with chunk bank-swizzle (chunk ^= (e>>1)&3) in the per-lane source address.
// The K/V tile is staged ONCE per CU (16 waves share): 2 gl_lds16 per wave per tile.
// Double-buffered, one barrier per tile; stage pinned between QK^T and softmax.
__global__ __launch_bounds__(1024, 4) void diff_attn(
    const bf16* __restrict__ Q, const bf16* __restrict__ Kb, const bf16* __restrict__ Vtg,
    const float* __restrict__ lq1, const float* __restrict__ lk1,
    const float* __restrict__ lq2, const float* __restrict__ lk2,
    const float* __restrict__ rms_scale, bf16* __restrict__ Ob) {
  constexpr int NSEQ = 2048, E = 2048, KT = 32, NT = NSEQ / KT;
  __shared__ __align__(16) char smem[65536];   // 2 x (K 16KB + V 16KB); epilogue: Zb[8][16][256] bf16
  bf16* Zb = (bf16*)smem;

  const int tid = threadIdx.x, lane = tid & 63, w = tid >> 6;
  const int l15 = lane & 15, lhi = lane >> 4;
  const int g = w >> 1, s = w & 1;

  // XCD-chunk swizzle: XCD k owns orig [k*32, (k+1)*32) -> 2 head-instances per XCD
  const int bid = blockIdx.x;
  const int orig = (bid & 7) * 32 + (bid >> 3);
  const int bh = orig >> 4;            // 0..15
  const int qb = orig & 15;            // 0..15
  const int b = bh >> 3, h = bh & 7;
  const int q0 = qb * 128;

  float lam = 0.f;
  if (s) {
    float sl1 = 0.f, sl2 = 0.f;
    for (int i = 0; i < 128; ++i) {
      sl1 += lq1[h * 128 + i] * lk1[h * 128 + i];
      sl2 += lq2[h * 128 + i] * lk2[h * 128 + i];
    }
    lam = __expf(sl1) - __expf(sl2) + LAMBDA_INIT_F;
  }

  // Q frags for this wave's stream (B-operand: col = l15 = q, k = lhi*8+j)
  const size_t qbase = ((size_t)b * NSEQ + q0 + g * 16 + l15) * E + (size_t)h * 256 + s * 128;
  bf16x8 qf[4];
#pragma unroll
  for (int df = 0; df < 4; ++df)
    qf[df] = *reinterpret_cast<const bf16x8*>(&Q[qbase + df * 32 + lhi * 8]);

  const bf16* Kbase = Kb + ((size_t)b * NSEQ) * E + (size_t)h * 256;
  const bf16* Vbase = Vtg + (((size_t)b * 8 + h) * 256) * (size_t)NSEQ;

  // staging invariants
  const int krow_sub = lane >> 5;      // 0/1: row within 1KB K chunk
  const int kslot = lane & 31;         // 16B slot in 512B K row
  const int ve_sub = lane >> 2;        // 0..15: e-row within 1KB V chunk
  const int vchunk = lane & 3;         // 16B chunk within 64B V row
  const int swz = l15 & 7;
  const int vq2 = (l15 >> 1) & 3;      // V read swizzle key
  const int voff = (lhi ^ vq2) << 3;   // element offset of 16B within V row

  f32x4 o[16] = {};
  float ll = 0.f;

  // 32 chunks of 1KB per tile (16 K + 16 V) over 16 waves: 2 per wave
  auto stage = [&](int buf, int t) {
    const int kt0 = t * KT;
    bf16* Ksl = (bf16*)(smem + buf * 32768);
    bf16* Vsl = Ksl + 8192;
    if (w < 8) {
#pragma unroll
      for (int i = 0; i < 2; ++i) {
        int c = w * 2 + i;
        int row = 2 * c + krow_sub;
        gl_lds16(&Kbase[(size_t)(kt0 + row) * E + ((kslot ^ (row & 7)) << 3)], &Ksl[c * 512]);
      }
    } else {
#pragma unroll
      for (int i = 0; i < 2; ++i) {
        int c = (w - 8) * 2 + i;
        int e = c * 16 + ve_sub;
        int lc = vchunk ^ ((e >> 1) & 3);
        gl_lds16(&Vbase[(size_t)e * NSEQ + kt0 + (lc << 3)], &Vsl[c * 512]);
      }
    }
  };

  stage(0, 0);
  __syncthreads();                     // tile 0 resident

  for (int t = 0; t < NT; ++t) {
    const int buf = t & 1;
    const bf16* Ksl = (const bf16*)(smem + buf * 32768);
    const bf16* Vsl = Ksl + 8192;

    // QK^T swapped (one stream): sv[cb][r] = S[key = cb*16 + 4*lhi + r][q = l15]
    f32x4 sv0 = {}, sv1 = {};
#pragma unroll
    for (int df = 0; df < 4; ++df) {
      const int slot = (((s << 4) + df * 4 + lhi) ^ swz) << 3;
      bf16x8 kf0 = *reinterpret_cast<const bf16x8*>(&Ksl[l15 * 256 + slot]);
      bf16x8 kf1 = *reinterpret_cast<const bf16x8*>(&Ksl[(16 + l15) * 256 + slot]);
      sv0 = __builtin_amdgcn_mfma_f32_16x16x32_bf16(kf0, qf[df], sv0, 0, 0, 0);
      sv1 = __builtin_amdgcn_mfma_f32_16x16x32_bf16(kf1, qf[df], sv1, 0, 0, 0);
    }

    // prefetch next tile: pinned so QK^T starts at barrier-exit; staging issue
    // overlaps the exp2 chain below.
    __builtin_amdgcn_sched_barrier(0);
    if (t + 1 < NT) stage(buf ^ 1, t + 1);
    __builtin_amdgcn_sched_barrier(0);

    // max-free softmax: P = 2^S directly (Q pre-scaled by SC*log2e)
    bf16 pb[8];
    float rsum = 0.f;
#pragma unroll
    for (int r = 0; r < 4; ++r) {
      float e0 = __builtin_amdgcn_exp2f(sv0[r]);
      float e1 = __builtin_amdgcn_exp2f(sv1[r]);
      rsum += e0 + e1;
      pb[r] = (bf16)e0;
      pb[4 + r] = (bf16)e1;
    }
    ll += rsum;
    bf16x8 pa = *reinterpret_cast<const bf16x8*>(pb);

    __builtin_amdgcn_s_setprio(1);
#pragma unroll
    for (int eb = 0; eb < 16; ++eb) {
      bf16x8 vf = *reinterpret_cast<const bf16x8*>(&Vsl[(eb * 16 + l15) * 32 + voff]);
      o[eb] = __builtin_amdgcn_mfma_f32_16x16x32_bf16(pa, vf, o[eb], 0, 0, 0);
    }
    __builtin_amdgcn_s_setprio(0);

    __syncthreads();                   // drains next-tile loads; frees buf for overwrite
  }

  // epilogue: reduce l, cross-wave stream combine (bf16 Z) + RMS norm + store
  ll += __shfl_xor(ll, 16, 64);
  ll += __shfl_xor(ll, 32, 64);
  float L[4];
#pragma unroll
  for (int r = 0; r < 4; ++r) L[r] = __shfl(ll, 4 * lhi + r, 64);

  if (s) {
    bf16* Zg = Zb + g * 4096;
#pragma unroll
    for (int r = 0; r < 4; ++r) {
      float i2 = lam / L[r];
#pragma unroll
      for (int eb = 0; eb < 16; ++eb)
        Zg[(4 * lhi + r) * 256 + eb * 16 + l15] = (bf16)(o[eb][r] * i2);
    }
  }
  __syncthreads();
  if (!s) {
    const float osc = 1.0f - LAMBDA_INIT_F;
    const bf16* Zg = Zb + g * 4096;
#pragma unroll
    for (int r = 0; r < 4; ++r) {
      float i1 = 1.0f / L[r];
      float vals[16];
      float ssq = 0.f;
#pragma unroll
      for (int eb = 0; eb < 16; ++eb) {
        float v = o[eb][r] * i1 - (float)Zg[(4 * lhi + r) * 256 + eb * 16 + l15];
        vals[eb] = v;
        ssq += v * v;
      }
#pragma unroll
      for (int off = 1; off < 16; off <<= 1) ssq += __shfl_xor(ssq, off, 64);
      float rinv = rsqrtf(ssq * (1.0f / 256.0f) + RMS_EPS);
      const int q = q0 + g * 16 + 4 * lhi + r;
      const size_t ob = ((size_t)b * NSEQ + q) * E + (size_t)h * 256;
#pragma unroll
      for (int eb = 0; eb < 16; ++eb) {
        int e = eb * 16 + l15;
        Ob[ob + e] = (bf16)(vals[eb] * rinv * rms_scale[e] * osc);
      }
    }
  }
}

// ---------------------------------------------------------------- launch
extern "C" void kernel_launch(void* const* d_in, const int* in_sizes, int n_in,
                              void* d_out, int out_size, void* d_ws, size_t ws_size,
                              hipStream_t stream) {
  const float* X   = (const float*)d_in[0];
  const float* Wq  = (const float*)d_in[1];
  const float* Wk  = (const float*)d_in[2];
  const float* Wv  = (const float*)d_in[3];
  const float* Wo  = (const float*)d_in[4];
  const float* lq1 = (const float*)d_in[5];
  const float* lk1 = (const float*)d_in[6];
  const float* lq2 = (const float*)d_in[7];
  const float* lk2 = (const float*)d_in[8];
  const float* rs  = (const float*)d_in[9];
  float* out = (float*)d_out;

  constexpr size_t B = 2, NSEQ = 2048, D = 1024, E = 2048;
  constexpr size_t M = B * NSEQ;  // 4096

  char* ws = (char*)d_ws;
  bf16* Xb  = (bf16*)ws;                 // M*D
  bf16* Wqb = Xb + M * D;                // E*D  (Wqb/Wkb/Wvb contiguous -> [6144][1024])
  bf16* Wkb = Wqb + E * D;
  bf16* Wvb = Wkb + E * D;
  bf16* Wob = Wvb + E * D;               // D*E
  bf16* Qb  = Wob + D * E;               // M*E  (Qb/Kb/Vtb contiguous for fused epilogue)
  bf16* Kb  = Qb + M * E;
  bf16* Vtb = Kb + M * E;                // M*E, layout [b,h,e,perm(n)]
  bf16* Ob  = Vtb + M * E;               // M*E

  fused_cast<<<2048, 256, 0, stream>>>(X, Wq, Wk, Wv, Wo, Xb);

  gemm_bt<3, 128><<<dim3(1536), 256, 0, stream>>>(Xb, Wqb, Qb, (int)M, 6144, (int)D);

  diff_attn<<<dim3(256), 1024, 0, stream>>>(Qb, Kb, Vtb, lq1, lk1, lq2, lk2, rs, Ob);

  gemm_bt<1, 64><<<dim3(M / 64, D / 128), 256, 0, stream>>>(Ob, Wob, out, (int)M, (int)D, (int)E);
}

// Round 10
// 250.582 us; speedup vs baseline: 1.0010x; 1.0010x over previous
//
#include <hip/hip_runtime.h>
#include <hip/hip_bf16.h>

typedef __bf16 bf16;
typedef __attribute__((ext_vector_type(8))) __bf16 bf16x8;
typedef __attribute__((ext_vector_type(4))) float f32x4;
typedef __attribute__((ext_vector_type(16))) float f32x16;
typedef __attribute__((ext_vector_type(4))) unsigned int u32x4;

#define LAMBDA_INIT_F 0.3555090675909693f
#define RMS_EPS 1e-5f
// (1/sqrt(128)) * log2(e) : folded into Q so QK^T scores are ready for exp2
#define QSCALE_F 0.1275174053237f

__device__ __forceinline__ void gl_lds16(const bf16* g, bf16* l) {
  __builtin_amdgcn_global_load_lds(
      (const __attribute__((address_space(1))) unsigned int*)g,
      (__attribute__((address_space(3))) unsigned int*)l, 16, 0, 0);
}

// ---------------------------------------------------------------- fused cast f32 -> bf16
// Destinations contiguous in ws: Xb(4M) Wqb(2M) Wkb(2M) Wvb(2M) Wob(2M) elems.
// Wo region is pre-scaled by rms_scale[e&255] * (1-lambda_init): the RMS-norm's
// elementwise scale commutes through the output GEMM's columns.
__global__ void fused_cast(const float* __restrict__ X, const float* __restrict__ Wq,
                           const float* __restrict__ Wk, const float* __restrict__ Wv,
                           const float* __restrict__ Wo, const float* __restrict__ rs,
                           bf16* __restrict__ out) {
  constexpr int T4 = 3145728;          // 12M elems / 4
  constexpr float OSC = 1.0f - LAMBDA_INIT_F;
  int idx = blockIdx.x * blockDim.x + threadIdx.x;
  int stride = gridDim.x * blockDim.x;
  for (int i = idx; i < T4; i += stride) {
    const float* src;
    int off;
    bool isWo = false;
    if (i < 1048576)       { src = X;  off = i; }
    else if (i < 1572864)  { src = Wq; off = i - 1048576; }
    else if (i < 2097152)  { src = Wk; off = i - 1572864; }
    else if (i < 2621440)  { src = Wv; off = i - 2097152; }
    else                   { src = Wo; off = i - 2621440; isWo = true; }
    float4 v = reinterpret_cast<const float4*>(src)[off];
    if (isWo) {
      int r0 = (off * 4) & 255;        // e % 256 (row len 2048 divisible by 256)
      v.x *= rs[r0] * OSC; v.y *= rs[r0 + 1] * OSC;
      v.z *= rs[r0 + 2] * OSC; v.w *= rs[r0 + 3] * OSC;
    }
    bf16 o[4];
    o[0] = (bf16)v.x; o[1] = (bf16)v.y; o[2] = (bf16)v.z; o[3] = (bf16)v.w;
    *reinterpret_cast<ushort4*>(&out[(size_t)i * 4]) = *reinterpret_cast<const ushort4*>(o);
  }
}

// ---------------------------------------------------------------- bt-GEMM (global_load_lds, 2-phase dbuf)
// C[m,n] = sum_k A[m,k] * B[n,k]
// MODE 1: f32 row-major out.
// MODE 3: fused QKV epilogue (N=6144): region n>>11 == 0 -> Qb bf16 * QSCALE;
//         1 -> Kb bf16; 2 -> Vt[b,h,e,nseq] (plain e-major transpose).
template <int MODE, int BM>
__global__ __launch_bounds__(256) void gemm_bt(
    const bf16* __restrict__ A, const bf16* __restrict__ B,
    void* __restrict__ Cv, int M, int N, int K) {
  constexpr int BN = 128, BK = 32;
  constexpr int MF = BM / 32;
  constexpr int CA = BM / 16;
  __shared__ __align__(16) bf16 As[2][BM * BK];
  __shared__ __align__(16) bf16 Bs[2][BN * BK];
  const int tid = threadIdx.x, lane = tid & 63, w = tid >> 6;
  const int l15 = lane & 15, lhi = lane >> 4;
  const int wr = (w >> 1) * (BM / 2), wc = (w & 1) * 64;
  const int bm = blockIdx.x * BM, bn = blockIdx.y * BN;
  const int srow = lane >> 2, scol = (lane & 3) * 8;
  const int NTK = K / BK;
  f32x4 acc[MF][4] = {};

  auto stage = [&](int buf, int k0) {
#pragma unroll
    for (int i = 0; i < CA / 4; ++i) {
      int c = w * (CA / 4) + i;
      gl_lds16(&A[(size_t)(bm + c * 16 + srow) * K + k0 + scol], &As[buf][c * 512]);
    }
#pragma unroll
    for (int i = 0; i < 2; ++i) {
      int c = w * 2 + i;
      gl_lds16(&B[(size_t)(bn + c * 16 + srow) * K + k0 + scol], &Bs[buf][c * 512]);
    }
  };

  stage(0, 0);
  __syncthreads();
  for (int t = 0; t < NTK; ++t) {
    const int buf = t & 1;
    if (t + 1 < NTK) stage(buf ^ 1, (t + 1) * BK);
    bf16x8 af[MF], bfr[4];
#pragma unroll
    for (int mf = 0; mf < MF; ++mf)
      af[mf] = *reinterpret_cast<const bf16x8*>(&As[buf][(wr + mf * 16 + l15) * BK + lhi * 8]);
#pragma unroll
    for (int nf = 0; nf < 4; ++nf)
      bfr[nf] = *reinterpret_cast<const bf16x8*>(&Bs[buf][(wc + nf * 16 + l15) * BK + lhi * 8]);
#pragma unroll
    for (int mf = 0; mf < MF; ++mf)
#pragma unroll
      for (int nf = 0; nf < 4; ++nf)
        acc[mf][nf] = __builtin_amdgcn_mfma_f32_16x16x32_bf16(af[mf], bfr[nf], acc[mf][nf], 0, 0, 0);
    __syncthreads();
  }

#pragma unroll
  for (int mf = 0; mf < MF; ++mf)
#pragma unroll
    for (int nf = 0; nf < 4; ++nf)
#pragma unroll
      for (int r = 0; r < 4; ++r) {
        int m = bm + wr + mf * 16 + lhi * 4 + r;
        int n = bn + wc + nf * 16 + l15;
        if constexpr (MODE == 1) {
          ((float*)Cv)[(size_t)m * N + n] = acc[mf][nf][r];
        } else {
          int reg = n >> 11, nl = n & 2047;
          if (reg == 0) {
            ((bf16*)Cv)[(size_t)m * 2048 + nl] = (bf16)(acc[mf][nf][r] * QSCALE_F);
          } else if (reg == 1) {
            ((bf16*)Cv)[(size_t)(m + 4096) * 2048 + nl] = (bf16)acc[mf][nf][r];
          } else {
            // Vt[b, h, e, nseq] at Cv + 2*M*2048
            int bb = m >> 11, nq = m & 2047;
            int hh = nl >> 8, e = nl & 255;
            ((bf16*)Cv)[(size_t)16777216 + ((((size_t)bb * 8 + hh) * 256 + e) << 11) + nq] =
                (bf16)acc[mf][nf][r];
          }
        }
      }
}

// ---------------------------------------------------------------- differential flash attention (32x32 MFMA)
// grid 256 (1 block/CU, XCD-chunk swizzled), block 512 = 8 waves:
//   wave w: q-group g=w>>1 (32 rows of the 128-row q-tile), stream s=w&1.
// Swapped QK^T with mfma_32x32x16: S[key32][q32] = mfma(A=K, B=Q); lane (q=lane&31,
// hi=lane>>5) holds S rows crow(reg,hi)=(reg&3)+8*(reg>>2)+4*hi for its q.
// Max-free softmax via exp2 (Q pre-scaled by SC*log2e); per-lane partial l.
// PV: O^T[e32][q32] = mfma(A=V^T frag from LDS, B=P frag). P B-frag needs keys
// hi*8+j: half live in the partner lane (lane^32) -> cvt_pk pairs + shfl_xor(32)
// + per-word select rebuild the frag exactly.
// K LDS [32][256] with 16B-slot XOR swizzle (slot ^= key&7) folded into gl_lds16 src.
// V LDS [eb2|kh][hi][e32][8elem] (1KB chunks): linear lane dest, conflict-free reads,
// staged straight from plain Vt[b,h,e,n].
__global__ __launch_bounds__(512, 2) void diff_attn(
    const bf16* __restrict__ Q, const bf16* __restrict__ Kb, const bf16* __restrict__ Vtg,
    const float* __restrict__ lq1, const float* __restrict__ lk1,
    const float* __restrict__ lq2, const float* __restrict__ lk2,
    bf16* __restrict__ Ob) {
  constexpr int NSEQ = 2048, E = 2048, KT = 32, NT = NSEQ / KT;
  __shared__ __align__(16) char smem[65536];   // 2 x (K 16KB + V 16KB); epilogue: Z[4][128][32] u32
  const int tid = threadIdx.x, lane = tid & 63, w = tid >> 6;
  const int q = lane & 31, hi = lane >> 5;
  const int g = w >> 1, s = w & 1;

  // XCD-chunk swizzle: XCD k owns orig [k*32,(k+1)*32) -> 2 head-instances per XCD
  const int bid = blockIdx.x;
  const int orig = (bid & 7) * 32 + (bid >> 3);
  const int bh = orig >> 4, qb = orig & 15;
  const int b = bh >> 3, h = bh & 7;
  const int q0 = qb * 128;

  float lam = 0.f;
  if (s) {
    float sl1 = 0.f, sl2 = 0.f;
    for (int i = 0; i < 128; ++i) {
      sl1 += lq1[h * 128 + i] * lk1[h * 128 + i];
      sl2 += lq2[h * 128 + i] * lk2[h * 128 + i];
    }
    lam = __expf(sl1) - __expf(sl2) + LAMBDA_INIT_F;
  }

  // Q B-frags (col=lane&31=q, k=(lane>>5)*8+j), d-range = s*128 .. +128
  const bf16* Qr = Q + ((size_t)b * NSEQ + q0 + g * 32 + q) * E + h * 256 + s * 128 + hi * 8;
  bf16x8 qf[8];
#pragma unroll
  for (int df = 0; df < 8; ++df)
    qf[df] = *reinterpret_cast<const bf16x8*>(Qr + df * 16);

  const bf16* Kbase = Kb + (size_t)b * NSEQ * E + h * 256;
  const bf16* Vbase = Vtg + ((size_t)b * 8 + h) * 256 * (size_t)NSEQ;

  const int kslot = lane & 31;

  f32x16 o[8] = {};
  float ll = 0.f;

  // 32 chunks of 1KB per tile (16 K + 16 V) over 8 waves: 4 per wave
  auto stage = [&](int buf, int t) {
    const int kt0 = t * KT;
    bf16* Ksl = (bf16*)(smem + buf * 32768);
    bf16* Vsl = Ksl + 8192;
    if (w < 4) {
#pragma unroll
      for (int i = 0; i < 4; ++i) {
        int c = w * 4 + i;
        int row = 2 * c + hi;
        gl_lds16(&Kbase[(size_t)(kt0 + row) * E + ((kslot ^ (row & 7)) << 3)], &Ksl[c * 512]);
      }
    } else {
#pragma unroll
      for (int i = 0; i < 4; ++i) {
        int c = (w - 4) * 4 + i;             // c = eb*2 + kh
        int erow = (c >> 1) * 32 + q;
        int koff = (c & 1) * 16 + hi * 8;
        gl_lds16(&Vbase[(size_t)erow * NSEQ + kt0 + koff], &Vsl[c * 512]);
      }
    }
  };

  stage(0, 0);
  __syncthreads();                     // tile 0 resident

  for (int t = 0; t < NT; ++t) {
    const int buf = t & 1;
    const bf16* Ksl = (const bf16*)(smem + buf * 32768);
    const bf16* Vsl = Ksl + 8192;

    // QK^T swapped: sv accumulates S^raw[key=crow(reg,hi)][q]
    f32x16 sv0 = {}, sv1 = {};
#pragma unroll
    for (int df = 0; df < 8; df += 2) {
      int sl0 = ((s * 16 + df * 2 + hi) ^ (q & 7)) << 3;
      bf16x8 kf0 = *reinterpret_cast<const bf16x8*>(&Ksl[q * 256 + sl0]);
      sv0 = __builtin_amdgcn_mfma_f32_32x32x16_bf16(kf0, qf[df], sv0, 0, 0, 0);
      int sl1 = ((s * 16 + (df + 1) * 2 + hi) ^ (q & 7)) << 3;
      bf16x8 kf1 = *reinterpret_cast<const bf16x8*>(&Ksl[q * 256 + sl1]);
      sv1 = __builtin_amdgcn_mfma_f32_32x32x16_bf16(kf1, qf[df + 1], sv1, 0, 0, 0);
    }

    // prefetch next tile (pinned: QK^T starts at barrier-exit; staging overlaps softmax)
    __builtin_amdgcn_sched_barrier(0);
    if (t + 1 < NT) stage(buf ^ 1, t + 1);
    __builtin_amdgcn_sched_barrier(0);

    // max-free softmax: P = 2^S
    float p[16];
#pragma unroll
    for (int r = 0; r < 16; ++r) {
      p[r] = __builtin_amdgcn_exp2f(sv0[r] + sv1[r]);
      ll += p[r];
    }

    // pack pairs to bf16 and rebuild PV B-frags (partner words via shfl_xor 32)
    unsigned int pkw[8], pw[8];
#pragma unroll
    for (int jj = 0; jj < 8; ++jj) {
      unsigned int u;
      asm("v_cvt_pk_bf16_f32 %0, %1, %2" : "=v"(u) : "v"(p[2 * jj]), "v"(p[2 * jj + 1]));
      pkw[jj] = u;
    }
#pragma unroll
    for (int jj = 0; jj < 8; ++jj)
      pw[jj] = (unsigned int)__shfl_xor((int)pkw[jj], 32, 64);

    u32x4 f0, f1;
    f0[0] = hi ? pw[2] : pkw[0];
    f0[1] = hi ? pw[3] : pkw[1];
    f0[2] = hi ? pkw[2] : pw[0];
    f0[3] = hi ? pkw[3] : pw[1];
    f1[0] = hi ? pw[6] : pkw[4];
    f1[1] = hi ? pw[7] : pkw[5];
    f1[2] = hi ? pkw[6] : pw[4];
    f1[3] = hi ? pkw[7] : pw[5];
    bf16x8 pb0 = __builtin_bit_cast(bf16x8, f0);
    bf16x8 pb1 = __builtin_bit_cast(bf16x8, f1);

    __builtin_amdgcn_s_setprio(1);
#pragma unroll
    for (int eb = 0; eb < 8; ++eb) {
      bf16x8 va = *reinterpret_cast<const bf16x8*>(&Vsl[(eb * 2) * 512 + lane * 8]);
      o[eb] = __builtin_amdgcn_mfma_f32_32x32x16_bf16(va, pb0, o[eb], 0, 0, 0);
      bf16x8 vb = *reinterpret_cast<const bf16x8*>(&Vsl[(eb * 2 + 1) * 512 + lane * 8]);
      o[eb] = __builtin_amdgcn_mfma_f32_32x32x16_bf16(vb, pb1, o[eb], 0, 0, 0);
    }
    __builtin_amdgcn_s_setprio(0);

    __syncthreads();                   // drains next-tile loads; frees buf
  }

  // epilogue: full l per q, stream combine via packed-bf16 Z, RMS (rinv only;
  // rms_scale*(1-lam_init) is folded into Wo), store.
  ll += __shfl_xor(ll, 32, 64);
  unsigned int* Zg = (unsigned int*)smem + g * 4096;   // [128 e2][32 q] u32

  if (s) {
    float i2 = lam / ll;
#pragma unroll
    for (int eb = 0; eb < 8; ++eb)
#pragma unroll
      for (int j = 0; j < 8; ++j) {
        int r0 = 2 * j;
        int crow0 = (r0 & 3) + 8 * (r0 >> 2) + 4 * hi;
        int e2 = eb * 16 + (crow0 >> 1);
        float z0 = o[eb][2 * j] * i2, z1 = o[eb][2 * j + 1] * i2;
        unsigned int u;
        asm("v_cvt_pk_bf16_f32 %0, %1, %2" : "=v"(u) : "v"(z0), "v"(z1));
        Zg[e2 * 32 + q] = u;
      }
  }
  __syncthreads();
  if (!s) {
    float i1 = 1.0f / ll;
    float ssq = 0.f;
#pragma unroll
    for (int eb = 0; eb < 8; ++eb)
#pragma unroll
      for (int j = 0; j < 8; ++j) {
        int r0 = 2 * j;
        int crow0 = (r0 & 3) + 8 * (r0 >> 2) + 4 * hi;
        int e2 = eb * 16 + (crow0 >> 1);
        unsigned int u = Zg[e2 * 32 + q];
        float z0 = __uint_as_float(u << 16);
        float z1 = __uint_as_float(u & 0xffff0000u);
        float v0 = o[eb][2 * j] * i1 - z0;
        float v1 = o[eb][2 * j + 1] * i1 - z1;
        o[eb][2 * j] = v0;
        o[eb][2 * j + 1] = v1;
        ssq += v0 * v0 + v1 * v1;
      }
    ssq += __shfl_xor(ssq, 32, 64);
    float rinv = rsqrtf(ssq * (1.0f / 256.0f) + RMS_EPS);
    unsigned int* Og = (unsigned int*)Ob;
    const size_t orow = ((size_t)b * NSEQ + q0 + g * 32 + q) * E + h * 256;
#pragma unroll
    for (int eb = 0; eb < 8; ++eb)
#pragma unroll
      for (int j = 0; j < 8; ++j) {
        int r0 = 2 * j;
        int crow0 = (r0 & 3) + 8 * (r0 >> 2) + 4 * hi;
        float v0 = o[eb][2 * j] * rinv, v1 = o[eb][2 * j + 1] * rinv;
        unsigned int u;
        asm("v_cvt_pk_bf16_f32 %0, %1, %2" : "=v"(u) : "v"(v0), "v"(v1));
        Og[(orow + eb * 32 + crow0) >> 1] = u;
      }
  }
}

// ---------------------------------------------------------------- launch
extern "C" void kernel_launch(void* const* d_in, const int* in_sizes, int n_in,
                              void* d_out, int out_size, void* d_ws, size_t ws_size,
                              hipStream_t stream) {
  const float* X   = (const float*)d_in[0];
  const float* Wq  = (const float*)d_in[1];
  const float* Wk  = (const float*)d_in[2];
  const float* Wv  = (const float*)d_in[3];
  const float* Wo  = (const float*)d_in[4];
  const float* lq1 = (const float*)d_in[5];
  const float* lk1 = (const float*)d_in[6];
  const float* lq2 = (const float*)d_in[7];
  const float* lk2 = (const float*)d_in[8];
  const float* rs  = (const float*)d_in[9];
  float* out = (float*)d_out;

  constexpr size_t B = 2, NSEQ = 2048, D = 1024, E = 2048;
  constexpr size_t M = B * NSEQ;  // 4096

  char* ws = (char*)d_ws;
  bf16* Xb  = (bf16*)ws;                 // M*D
  bf16* Wqb = Xb + M * D;                // E*D  (Wqb/Wkb/Wvb contiguous -> [6144][1024])
  bf16* Wkb = Wqb + E * D;
  bf16* Wvb = Wkb + E * D;
  bf16* Wob = Wvb + E * D;               // D*E (pre-scaled by rs*osc)
  bf16* Qb  = Wob + D * E;               // M*E  (Qb/Kb/Vtb contiguous for fused epilogue)
  bf16* Kb  = Qb + M * E;
  bf16* Vtb = Kb + M * E;                // M*E, layout [b,h,e,n]
  bf16* Ob  = Vtb + M * E;               // M*E

  fused_cast<<<2048, 256, 0, stream>>>(X, Wq, Wk, Wv, Wo, rs, Xb);

  gemm_bt<3, 128><<<dim3(M / 128, 6144 / 128), 256, 0, stream>>>(
      Xb, Wqb, Qb, (int)M, 6144, (int)D);

  diff_attn<<<dim3(256), 512, 0, stream>>>(Qb, Kb, Vtb, lq1, lk1, lq2, lk2, Ob);

  gemm_bt<1, 64><<<dim3(M / 64, D / 128), 256, 0, stream>>>(Ob, Wob, out, (int)M, (int)D, (int)E);
}

// Round 11
// 243.476 us; speedup vs baseline: 1.0302x; 1.0292x over previous
//
#include <hip/hip_runtime.h>
#include <hip/hip_bf16.h>

typedef __bf16 bf16;
typedef __attribute__((ext_vector_type(8))) __bf16 bf16x8;
typedef __attribute__((ext_vector_type(4))) float f32x4;

#define LAMBDA_INIT_F 0.3555090675909693f
#define RMS_EPS 1e-5f
// (1/sqrt(128)) * log2(e) : folded into Q so QK^T scores are ready for exp2
#define QSCALE_F 0.1275174053237f

__device__ __forceinline__ void gl_lds16(const bf16* g, bf16* l) {
  __builtin_amdgcn_global_load_lds(
      (const __attribute__((address_space(1))) unsigned int*)g,
      (__attribute__((address_space(3))) unsigned int*)l, 16, 0, 0);
}

// ---------------------------------------------------------------- fused cast f32 -> bf16
// Destinations contiguous in ws: Xb(4M) Wqb(2M) Wkb(2M) Wvb(2M) Wob(2M) elems.
// Wo region is pre-scaled by rms_scale[col&255] * (1-lambda_init): the RMS-norm's
// elementwise scale commutes through the output GEMM's columns.
__global__ void fused_cast(const float* __restrict__ X, const float* __restrict__ Wq,
                           const float* __restrict__ Wk, const float* __restrict__ Wv,
                           const float* __restrict__ Wo, const float* __restrict__ rs,
                           bf16* __restrict__ out) {
  constexpr int T4 = 3145728;          // 12M elems / 4
  constexpr float OSC = 1.0f - LAMBDA_INIT_F;
  int idx = blockIdx.x * blockDim.x + threadIdx.x;
  int stride = gridDim.x * blockDim.x;
  for (int i = idx; i < T4; i += stride) {
    const float* src;
    int off;
    bool isWo = false;
    if (i < 1048576)       { src = X;  off = i; }
    else if (i < 1572864)  { src = Wq; off = i - 1048576; }
    else if (i < 2097152)  { src = Wk; off = i - 1572864; }
    else if (i < 2621440)  { src = Wv; off = i - 2097152; }
    else                   { src = Wo; off = i - 2621440; isWo = true; }
    float4 v = reinterpret_cast<const float4*>(src)[off];
    if (isWo) {
      int r0 = (off * 4) & 255;        // col % 256 (row len 2048 divisible by 256)
      v.x *= rs[r0] * OSC; v.y *= rs[r0 + 1] * OSC;
      v.z *= rs[r0 + 2] * OSC; v.w *= rs[r0 + 3] * OSC;
    }
    bf16 o[4];
    o[0] = (bf16)v.x; o[1] = (bf16)v.y; o[2] = (bf16)v.z; o[3] = (bf16)v.w;
    *reinterpret_cast<ushort4*>(&out[(size_t)i * 4]) = *reinterpret_cast<const ushort4*>(o);
  }
}

// ---------------------------------------------------------------- bt-GEMM (global_load_lds, 2-phase dbuf)
// C[m,n] = sum_k A[m,k] * B[n,k]
// MODE 1: f32 row-major out.
// MODE 3: fused QKV epilogue (N=6144): region n>>11 == 0 -> Qb bf16 * QSCALE;
//         1 -> Kb bf16; 2 -> Vt[b,h,e, perm(nseq)] where within each 32-key group the
//         key is stored at its PV A-frag slot: key 16h+4g+c -> slot 8g+4h+c. This makes
//         attention's V staging 16B-contiguous gl_lds16.
template <int MODE, int BM>
__global__ __launch_bounds__(256) void gemm_bt(
    const bf16* __restrict__ A, const bf16* __restrict__ B,
    void* __restrict__ Cv, int M, int N, int K) {
  constexpr int BN = 128, BK = 32;
  constexpr int MF = BM / 32;
  constexpr int CA = BM / 16;
  __shared__ __align__(16) bf16 As[2][BM * BK];
  __shared__ __align__(16) bf16 Bs[2][BN * BK];
  const int tid = threadIdx.x, lane = tid & 63, w = tid >> 6;
  const int l15 = lane & 15, lhi = lane >> 4;
  const int wr = (w >> 1) * (BM / 2), wc = (w & 1) * 64;
  const int bm = blockIdx.x * BM, bn = blockIdx.y * BN;
  const int srow = lane >> 2, scol = (lane & 3) * 8;
  const int NTK = K / BK;
  f32x4 acc[MF][4] = {};

  auto stage = [&](int buf, int k0) {
#pragma unroll
    for (int i = 0; i < CA / 4; ++i) {
      int c = w * (CA / 4) + i;
      gl_lds16(&A[(size_t)(bm + c * 16 + srow) * K + k0 + scol], &As[buf][c * 512]);
    }
#pragma unroll
    for (int i = 0; i < 2; ++i) {
      int c = w * 2 + i;
      gl_lds16(&B[(size_t)(bn + c * 16 + srow) * K + k0 + scol], &Bs[buf][c * 512]);
    }
  };

  stage(0, 0);
  __syncthreads();
  for (int t = 0; t < NTK; ++t) {
    const int buf = t & 1;
    if (t + 1 < NTK) stage(buf ^ 1, (t + 1) * BK);
    bf16x8 af[MF], bfr[4];
#pragma unroll
    for (int mf = 0; mf < MF; ++mf)
      af[mf] = *reinterpret_cast<const bf16x8*>(&As[buf][(wr + mf * 16 + l15) * BK + lhi * 8]);
#pragma unroll
    for (int nf = 0; nf < 4; ++nf)
      bfr[nf] = *reinterpret_cast<const bf16x8*>(&Bs[buf][(wc + nf * 16 + l15) * BK + lhi * 8]);
#pragma unroll
    for (int mf = 0; mf < MF; ++mf)
#pragma unroll
      for (int nf = 0; nf < 4; ++nf)
        acc[mf][nf] = __builtin_amdgcn_mfma_f32_16x16x32_bf16(af[mf], bfr[nf], acc[mf][nf], 0, 0, 0);
    __syncthreads();
  }

#pragma unroll
  for (int mf = 0; mf < MF; ++mf)
#pragma unroll
    for (int nf = 0; nf < 4; ++nf)
#pragma unroll
      for (int r = 0; r < 4; ++r) {
        int m = bm + wr + mf * 16 + lhi * 4 + r;
        int n = bn + wc + nf * 16 + l15;
        if constexpr (MODE == 1) {
          ((float*)Cv)[(size_t)m * N + n] = acc[mf][nf][r];
        } else {
          int reg = n >> 11, nl = n & 2047;
          if (reg == 0) {
            ((bf16*)Cv)[(size_t)m * 2048 + nl] = (bf16)(acc[mf][nf][r] * QSCALE_F);
          } else if (reg == 1) {
            ((bf16*)Cv)[(size_t)(m + 4096) * 2048 + nl] = (bf16)acc[mf][nf][r];
          } else {
            // Vt[b, h, e, perm(nseq)] at Cv + 2*M*2048
            int bb = m >> 11, nq = m & 2047;
            int hh = nl >> 8, e = nl & 255;
            int k5 = nq & 31;
            int slot = (((k5 >> 2) & 3) << 3) | (((k5 >> 4) & 1) << 2) | (k5 & 3);
            int np = (nq & ~31) | slot;
            ((bf16*)Cv)[(size_t)16777216 + ((((size_t)bb * 8 + hh) * 256 + e) << 11) + np] =
                (bf16)acc[mf][nf][r];
          }
        }
      }
}

// ---------------------------------------------------------------- differential flash attention
// 1D grid 512 (XCD-chunk swizzled), block 512 = 8 waves: q-group g=w>>1 (16 rows), stream s=w&1.
// q-tile = 64 rows. Swapped QK^T -> lane holds 8 P-values of q-row l15.
// Max-free softmax via exp2 (Q pre-scaled by SC*log2e); per-lane partial l, reduced in epilogue.
// K in LDS [32][256] with 16B-slot XOR swizzle folded into gl_lds16 source.
// V global layout is slot-permuted (GEMM MODE-3): staging is 16B-contiguous gl_lds16
// with chunk bank-swizzle (chunk ^= (e>>1)&3) in the per-lane source address.
// Double-buffered, one barrier per tile. Stage-issue pinned between QK^T and softmax.
// RMS scale & (1-lambda_init) are folded into Wo: epilogue applies rinv only.
__global__ __launch_bounds__(512, 4) void diff_attn(
    const bf16* __restrict__ Q, const bf16* __restrict__ Kb, const bf16* __restrict__ Vtg,
    const float* __restrict__ lq1, const float* __restrict__ lk1,
    const float* __restrict__ lq2, const float* __restrict__ lk2,
    bf16* __restrict__ Ob) {
  constexpr int NSEQ = 2048, E = 2048, KT = 32, NT = NSEQ / KT;
  __shared__ __align__(16) char smem[65536];   // 2 x (K 16KB + V 16KB); epilogue: Zb[4][16][256] bf16
  bf16* Zb = (bf16*)smem;

  const int tid = threadIdx.x, lane = tid & 63, w = tid >> 6;
  const int l15 = lane & 15, lhi = lane >> 4;
  const int g = w >> 1, s = w & 1;

  // XCD-chunk swizzle: XCD k owns orig [k*64, (k+1)*64) -> 2 head-instances per XCD
  const int bid = blockIdx.x;
  const int orig = (bid & 7) * 64 + (bid >> 3);
  const int bh = orig >> 5;
  const int qb = orig & 31;
  const int b = bh >> 3, h = bh & 7;
  const int q0 = qb * 64;

  float lam = 0.f;
  if (s) {
    float sl1 = 0.f, sl2 = 0.f;
    for (int i = 0; i < 128; ++i) {
      sl1 += lq1[h * 128 + i] * lk1[h * 128 + i];
      sl2 += lq2[h * 128 + i] * lk2[h * 128 + i];
    }
    lam = __expf(sl1) - __expf(sl2) + LAMBDA_INIT_F;
  }

  // Q frags for this wave's stream (B-operand: col = l15 = q, k = lhi*8+j)
  const size_t qbase = ((size_t)b * NSEQ + q0 + g * 16 + l15) * E + (size_t)h * 256 + s * 128;
  bf16x8 qf[4];
#pragma unroll
  for (int df = 0; df < 4; ++df)
    qf[df] = *reinterpret_cast<const bf16x8*>(&Q[qbase + df * 32 + lhi * 8]);

  const bf16* Kbase = Kb + ((size_t)b * NSEQ) * E + (size_t)h * 256;
  const bf16* Vbase = Vtg + (((size_t)b * 8 + h) * 256) * (size_t)NSEQ;

  // staging invariants
  const int krow_sub = lane >> 5;      // 0/1: row within 1KB K chunk
  const int kslot = lane & 31;         // 16B slot in 512B K row
  const int ve_sub = lane >> 2;        // 0..15: e-row within 1KB V chunk
  const int vchunk = lane & 3;         // 16B chunk within 64B V row
  const int swz = l15 & 7;
  const int vq2 = (l15 >> 1) & 3;      // V read swizzle key
  const int voff = (lhi ^ vq2) << 3;   // element offset of 16B within V row

  f32x4 o[16] = {};
  float ll = 0.f;

  auto stage = [&](int buf, int t) {
    const int kt0 = t * KT;
    bf16* Ksl = (bf16*)(smem + buf * 32768);
    bf16* Vsl = Ksl + 8192;
    // K: 16 chunks x 1KB (2 rows each), source 16B-slot pre-swizzled
#pragma unroll
    for (int i = 0; i < 2; ++i) {
      int c = w * 2 + i;
      int row = 2 * c + krow_sub;
      gl_lds16(&Kbase[(size_t)(kt0 + row) * E + ((kslot ^ (row & 7)) << 3)], &Ksl[c * 512]);
    }
    // V: 16 chunks x 1KB (16 e-rows x 64B); slot-permuted global + chunk bank-swizzle in src
#pragma unroll
    for (int i = 0; i < 2; ++i) {
      int c = w * 2 + i;
      int e = c * 16 + ve_sub;
      int lc = vchunk ^ ((e >> 1) & 3);
      gl_lds16(&Vbase[(size_t)e * NSEQ + kt0 + (lc << 3)], &Vsl[c * 512]);
    }
  };

  stage(0, 0);
  __syncthreads();                     // tile 0 resident

  for (int t = 0; t < NT; ++t) {
    const int buf = t & 1;
    const bf16* Ksl = (const bf16*)(smem + buf * 32768);
    const bf16* Vsl = Ksl + 8192;

    // QK^T swapped (one stream): sv[cb][r] = S[key = cb*16 + 4*lhi + r][q = l15]
    f32x4 sv0 = {}, sv1 = {};
#pragma unroll
    for (int df = 0; df < 4; ++df) {
      const int slot = (((s << 4) + df * 4 + lhi) ^ swz) << 3;
      bf16x8 kf0 = *reinterpret_cast<const bf16x8*>(&Ksl[l15 * 256 + slot]);
      bf16x8 kf1 = *reinterpret_cast<const bf16x8*>(&Ksl[(16 + l15) * 256 + slot]);
      sv0 = __builtin_amdgcn_mfma_f32_16x16x32_bf16(kf0, qf[df], sv0, 0, 0, 0);
      sv1 = __builtin_amdgcn_mfma_f32_16x16x32_bf16(kf1, qf[df], sv1, 0, 0, 0);
    }

    // prefetch next tile: pinned here so QK^T MFMAs start immediately at barrier-exit
    // and the staging VALU/VMEM issue overlaps the exp2 chain below.
    __builtin_amdgcn_sched_barrier(0);
    if (t + 1 < NT) stage(buf ^ 1, t + 1);
    __builtin_amdgcn_sched_barrier(0);

    // max-free softmax: P = 2^S directly (Q pre-scaled by SC*log2e)
    bf16 pb[8];
    float rsum = 0.f;
#pragma unroll
    for (int r = 0; r < 4; ++r) {
      float e0 = __builtin_amdgcn_exp2f(sv0[r]);
      float e1 = __builtin_amdgcn_exp2f(sv1[r]);
      rsum += e0 + e1;
      pb[r] = (bf16)e0;
      pb[4 + r] = (bf16)e1;
    }
    ll += rsum;
    bf16x8 pa = *reinterpret_cast<const bf16x8*>(pb);

    __builtin_amdgcn_s_setprio(1);
#pragma unroll
    for (int eb = 0; eb < 16; ++eb) {
      bf16x8 vf = *reinterpret_cast<const bf16x8*>(&Vsl[(eb * 16 + l15) * 32 + voff]);
      o[eb] = __builtin_amdgcn_mfma_f32_16x16x32_bf16(pa, vf, o[eb], 0, 0, 0);
    }
    __builtin_amdgcn_s_setprio(0);

    __syncthreads();                   // drains next-tile loads; frees buf for overwrite
  }

  // epilogue: reduce l, cross-wave stream combine (bf16 Z) + RMS rinv + store
  ll += __shfl_xor(ll, 16, 64);
  ll += __shfl_xor(ll, 32, 64);
  float L[4];
#pragma unroll
  for (int r = 0; r < 4; ++r) L[r] = __shfl(ll, 4 * lhi + r, 64);

  if (s) {
    bf16* Zg = Zb + g * 4096;
#pragma unroll
    for (int r = 0; r < 4; ++r) {
      float i2 = lam / L[r];
#pragma unroll
      for (int eb = 0; eb < 16; ++eb)
        Zg[(4 * lhi + r) * 256 + eb * 16 + l15] = (bf16)(o[eb][r] * i2);
    }
  }
  __syncthreads();
  if (!s) {
    const bf16* Zg = Zb + g * 4096;
#pragma unroll
    for (int r = 0; r < 4; ++r) {
      float i1 = 1.0f / L[r];
      float vals[16];
      float ssq = 0.f;
#pragma unroll
      for (int eb = 0; eb < 16; ++eb) {
        float v = o[eb][r] * i1 - (float)Zg[(4 * lhi + r) * 256 + eb * 16 + l15];
        vals[eb] = v;
        ssq += v * v;
      }
#pragma unroll
      for (int off = 1; off < 16; off <<= 1) ssq += __shfl_xor(ssq, off, 64);
      float rinv = rsqrtf(ssq * (1.0f / 256.0f) + RMS_EPS);
      const int q = q0 + g * 16 + 4 * lhi + r;
      const size_t ob = ((size_t)b * NSEQ + q) * E + (size_t)h * 256;
#pragma unroll
      for (int eb = 0; eb < 16; ++eb) {
        int e = eb * 16 + l15;
        Ob[ob + e] = (bf16)(vals[eb] * rinv);
      }
    }
  }
}

// ---------------------------------------------------------------- launch
extern "C" void kernel_launch(void* const* d_in, const int* in_sizes, int n_in,
                              void* d_out, int out_size, void* d_ws, size_t ws_size,
                              hipStream_t stream) {
  const float* X   = (const float*)d_in[0];
  const float* Wq  = (const float*)d_in[1];
  const float* Wk  = (const float*)d_in[2];
  const float* Wv  = (const float*)d_in[3];
  const float* Wo  = (const float*)d_in[4];
  const float* lq1 = (const float*)d_in[5];
  const float* lk1 = (const float*)d_in[6];
  const float* lq2 = (const float*)d_in[7];
  const float* lk2 = (const float*)d_in[8];
  const float* rs  = (const float*)d_in[9];
  float* out = (float*)d_out;

  constexpr size_t B = 2, NSEQ = 2048, D = 1024, E = 2048;
  constexpr size_t M = B * NSEQ;  // 4096

  char* ws = (char*)d_ws;
  bf16* Xb  = (bf16*)ws;                 // M*D
  bf16* Wqb = Xb + M * D;                // E*D  (Wqb/Wkb/Wvb contiguous -> [6144][1024])
  bf16* Wkb = Wqb + E * D;
  bf16* Wvb = Wkb + E * D;
  bf16* Wob = Wvb + E * D;               // D*E (pre-scaled by rs*osc)
  bf16* Qb  = Wob + D * E;               // M*E  (Qb/Kb/Vtb contiguous for fused epilogue)
  bf16* Kb  = Qb + M * E;
  bf16* Vtb = Kb + M * E;                // M*E, layout [b,h,e,perm(n)]
  bf16* Ob  = Vtb + M * E;               // M*E

  fused_cast<<<2048, 256, 0, stream>>>(X, Wq, Wk, Wv, Wo, rs, Xb);

  gemm_bt<3, 128><<<dim3(M / 128, 6144 / 128), 256, 0, stream>>>(
      Xb, Wqb, Qb, (int)M, 6144, (int)D);

  diff_attn<<<dim3(512), 512, 0, stream>>>(Qb, Kb, Vtb, lq1, lk1, lq2, lk2, Ob);

  gemm_bt<1, 128><<<dim3(M / 128, D / 128), 256, 0, stream>>>(Ob, Wob, out, (int)M, (int)D, (int)E);
}

// Round 12
// 236.813 us; speedup vs baseline: 1.0592x; 1.0281x over previous
//
#include <hip/hip_runtime.h>
#include <hip/hip_bf16.h>

typedef __bf16 bf16;
typedef __attribute__((ext_vector_type(8))) __bf16 bf16x8;
typedef __attribute__((ext_vector_type(4))) float f32x4;

#define LAMBDA_INIT_F 0.3555090675909693f
#define RMS_EPS 1e-5f
// (1/sqrt(128)) * log2(e) : folded into Q so QK^T scores are ready for exp2
#define QSCALE_F 0.1275174053237f

__device__ __forceinline__ void gl_lds16(const bf16* g, bf16* l) {
  __builtin_amdgcn_global_load_lds(
      (const __attribute__((address_space(1))) unsigned int*)g,
      (__attribute__((address_space(3))) unsigned int*)l, 16, 0, 0);
}

// ---------------------------------------------------------------- fused cast f32 -> bf16
// Destinations contiguous in ws: Xb(4M) Wqb(2M) Wkb(2M) Wvb(2M) Wob(2M) elems.
// Wo region is pre-scaled by rms_scale[col&255] * (1-lambda_init).
__global__ void fused_cast(const float* __restrict__ X, const float* __restrict__ Wq,
                           const float* __restrict__ Wk, const float* __restrict__ Wv,
                           const float* __restrict__ Wo, const float* __restrict__ rs,
                           bf16* __restrict__ out) {
  constexpr int T4 = 3145728;          // 12M elems / 4
  constexpr float OSC = 1.0f - LAMBDA_INIT_F;
  int idx = blockIdx.x * blockDim.x + threadIdx.x;
  int stride = gridDim.x * blockDim.x;
  for (int i = idx; i < T4; i += stride) {
    const float* src;
    int off;
    bool isWo = false;
    if (i < 1048576)       { src = X;  off = i; }
    else if (i < 1572864)  { src = Wq; off = i - 1048576; }
    else if (i < 2097152)  { src = Wk; off = i - 1572864; }
    else if (i < 2621440)  { src = Wv; off = i - 2097152; }
    else                   { src = Wo; off = i - 2621440; isWo = true; }
    float4 v = reinterpret_cast<const float4*>(src)[off];
    if (isWo) {
      int r0 = (off * 4) & 255;        // col % 256 (row len 2048 divisible by 256)
      v.x *= rs[r0] * OSC; v.y *= rs[r0 + 1] * OSC;
      v.z *= rs[r0 + 2] * OSC; v.w *= rs[r0 + 3] * OSC;
    }
    bf16 o[4];
    o[0] = (bf16)v.x; o[1] = (bf16)v.y; o[2] = (bf16)v.z; o[3] = (bf16)v.w;
    *reinterpret_cast<ushort4*>(&out[(size_t)i * 4]) = *reinterpret_cast<const ushort4*>(o);
  }
}

// ---------------------------------------------------------------- bt-GEMM (global_load_lds, 2-phase dbuf)
// C[m,n] = sum_k A[m,k] * B[n,k]
// MODE 1: f32 row-major out.
// MODE 3: fused QKV epilogue (N=6144): region n>>11 == 0 -> Qb bf16 * QSCALE;
//         1 -> Kb bf16; 2 -> Vt[b,h,e, perm(nseq)] (key 16h+4g+c -> slot 8g+4h+c,
//         so attention's V staging is 16B-contiguous gl_lds16).
template <int MODE, int BM>
__global__ __launch_bounds__(256) void gemm_bt(
    const bf16* __restrict__ A, const bf16* __restrict__ B,
    void* __restrict__ Cv, int M, int N, int K) {
  constexpr int BN = 128, BK = 32;
  constexpr int MF = BM / 32;
  constexpr int CA = BM / 16;
  __shared__ __align__(16) bf16 As[2][BM * BK];
  __shared__ __align__(16) bf16 Bs[2][BN * BK];
  const int tid = threadIdx.x, lane = tid & 63, w = tid >> 6;
  const int l15 = lane & 15, lhi = lane >> 4;
  const int wr = (w >> 1) * (BM / 2), wc = (w & 1) * 64;
  const int bm = blockIdx.x * BM, bn = blockIdx.y * BN;
  const int srow = lane >> 2, scol = (lane & 3) * 8;
  const int NTK = K / BK;
  f32x4 acc[MF][4] = {};

  auto stage = [&](int buf, int k0) {
#pragma unroll
    for (int i = 0; i < CA / 4; ++i) {
      int c = w * (CA / 4) + i;
      gl_lds16(&A[(size_t)(bm + c * 16 + srow) * K + k0 + scol], &As[buf][c * 512]);
    }
#pragma unroll
    for (int i = 0; i < 2; ++i) {
      int c = w * 2 + i;
      gl_lds16(&B[(size_t)(bn + c * 16 + srow) * K + k0 + scol], &Bs[buf][c * 512]);
    }
  };

  stage(0, 0);
  __syncthreads();
  for (int t = 0; t < NTK; ++t) {
    const int buf = t & 1;
    if (t + 1 < NTK) stage(buf ^ 1, (t + 1) * BK);
    bf16x8 af[MF], bfr[4];
#pragma unroll
    for (int mf = 0; mf < MF; ++mf)
      af[mf] = *reinterpret_cast<const bf16x8*>(&As[buf][(wr + mf * 16 + l15) * BK + lhi * 8]);
#pragma unroll
    for (int nf = 0; nf < 4; ++nf)
      bfr[nf] = *reinterpret_cast<const bf16x8*>(&Bs[buf][(wc + nf * 16 + l15) * BK + lhi * 8]);
#pragma unroll
    for (int mf = 0; mf < MF; ++mf)
#pragma unroll
      for (int nf = 0; nf < 4; ++nf)
        acc[mf][nf] = __builtin_amdgcn_mfma_f32_16x16x32_bf16(af[mf], bfr[nf], acc[mf][nf], 0, 0, 0);
    __syncthreads();
  }

#pragma unroll
  for (int mf = 0; mf < MF; ++mf)
#pragma unroll
    for (int nf = 0; nf < 4; ++nf)
#pragma unroll
      for (int r = 0; r < 4; ++r) {
        int m = bm + wr + mf * 16 + lhi * 4 + r;
        int n = bn + wc + nf * 16 + l15;
        if constexpr (MODE == 1) {
          ((float*)Cv)[(size_t)m * N + n] = acc[mf][nf][r];
        } else {
          int reg = n >> 11, nl = n & 2047;
          if (reg == 0) {
            ((bf16*)Cv)[(size_t)m * 2048 + nl] = (bf16)(acc[mf][nf][r] * QSCALE_F);
          } else if (reg == 1) {
            ((bf16*)Cv)[(size_t)(m + 4096) * 2048 + nl] = (bf16)acc[mf][nf][r];
          } else {
            // Vt[b, h, e, perm(nseq)] at Cv + 2*M*2048
            int bb = m >> 11, nq = m & 2047;
            int hh = nl >> 8, e = nl & 255;
            int k5 = nq & 31;
            int slot = (((k5 >> 2) & 3) << 3) | (((k5 >> 4) & 1) << 2) | (k5 & 3);
            int np = (nq & ~31) | slot;
            ((bf16*)Cv)[(size_t)16777216 + ((((size_t)bb * 8 + hh) * 256 + e) << 11) + np] =
                (bf16)acc[mf][nf][r];
          }
        }
      }
}

// ---------------------------------------------------------------- differential flash attention
// 1D grid 512 (XCD-chunk swizzled), block 256 = 4 waves: q-group g=w>>1 (32 rows),
// stream s=w&1. q-tile = 64 rows. Each wave owns 32 q-rows of ONE stream as two
// 16-row halves (lo: q=g*32+l15, hi: +16): every K fragment read feeds 2 QK MFMAs
// and every V fragment read feeds 2 PV MFMAs -> per-FLOP LDS traffic halved vs the
// 16-row structure, with P still fully in-lane (no cross-lane ops).
// Swapped QK^T -> lane holds 8 P-values per q-half. Max-free softmax via exp2
// (Q pre-scaled by SC*log2e); per-lane partial l per half, reduced in epilogue.
// K in LDS [32][256] with 16B-slot XOR swizzle folded into gl_lds16 source.
// V global layout is slot-permuted (GEMM MODE-3): staging is 16B-contiguous gl_lds16
// with chunk bank-swizzle (chunk ^= (e>>1)&3) in the per-lane source address.
// Double-buffered, one barrier per tile. Stage-issue pinned between QK^T and softmax.
// RMS scale & (1-lambda_init) folded into Wo: epilogue applies rinv only.
__global__ __launch_bounds__(256, 2) void diff_attn(
    const bf16* __restrict__ Q, const bf16* __restrict__ Kb, const bf16* __restrict__ Vtg,
    const float* __restrict__ lq1, const float* __restrict__ lk1,
    const float* __restrict__ lq2, const float* __restrict__ lk2,
    bf16* __restrict__ Ob) {
  constexpr int NSEQ = 2048, E = 2048, KT = 32, NT = NSEQ / KT;
  __shared__ __align__(16) char smem[65536];   // 2 x (K 16KB + V 16KB); epilogue: Zb[2][32][256] bf16
  bf16* Zb = (bf16*)smem;

  const int tid = threadIdx.x, lane = tid & 63, w = tid >> 6;
  const int l15 = lane & 15, lhi = lane >> 4;
  const int g = w >> 1, s = w & 1;

  // XCD-chunk swizzle: XCD k owns orig [k*64, (k+1)*64) -> 2 head-instances per XCD
  const int bid = blockIdx.x;
  const int orig = (bid & 7) * 64 + (bid >> 3);
  const int bh = orig >> 5;
  const int qb = orig & 31;
  const int b = bh >> 3, h = bh & 7;
  const int q0 = qb * 64;

  float lam = 0.f;
  if (s) {
    float sl1 = 0.f, sl2 = 0.f;
    for (int i = 0; i < 128; ++i) {
      sl1 += lq1[h * 128 + i] * lk1[h * 128 + i];
      sl2 += lq2[h * 128 + i] * lk2[h * 128 + i];
    }
    lam = __expf(sl1) - __expf(sl2) + LAMBDA_INIT_F;
  }

  // Q frags for the wave's two q-halves (B-operand: col=q, k=lhi*8+j)
  const size_t qbase = ((size_t)b * NSEQ + q0 + g * 32 + l15) * E + (size_t)h * 256 + s * 128;
  bf16x8 qlo[4], qhi[4];
#pragma unroll
  for (int df = 0; df < 4; ++df) {
    qlo[df] = *reinterpret_cast<const bf16x8*>(&Q[qbase + df * 32 + lhi * 8]);
    qhi[df] = *reinterpret_cast<const bf16x8*>(&Q[qbase + 16 * E + df * 32 + lhi * 8]);
  }

  const bf16* Kbase = Kb + ((size_t)b * NSEQ) * E + (size_t)h * 256;
  const bf16* Vbase = Vtg + (((size_t)b * 8 + h) * 256) * (size_t)NSEQ;

  // staging invariants
  const int krow_sub = lane >> 5;      // 0/1: row within 1KB K chunk
  const int kslot = lane & 31;         // 16B slot in 512B K row
  const int ve_sub = lane >> 2;        // 0..15: e-row within 1KB V chunk
  const int vchunk = lane & 3;         // 16B chunk within 64B V row
  const int swz = l15 & 7;
  const int vq2 = (l15 >> 1) & 3;      // V read swizzle key
  const int voff = (lhi ^ vq2) << 3;   // element offset of 16B within V row

  f32x4 olo[16] = {}, ohi[16] = {};
  float ll0 = 0.f, ll1 = 0.f;

  // 32 chunks of 1KB per tile (16 K + 16 V) over 4 waves: 8 per wave
  auto stage = [&](int buf, int t) {
    const int kt0 = t * KT;
    bf16* Ksl = (bf16*)(smem + buf * 32768);
    bf16* Vsl = Ksl + 8192;
    if (w < 2) {
#pragma unroll
      for (int i = 0; i < 8; ++i) {
        int c = w * 8 + i;
        int row = 2 * c + krow_sub;
        gl_lds16(&Kbase[(size_t)(kt0 + row) * E + ((kslot ^ (row & 7)) << 3)], &Ksl[c * 512]);
      }
    } else {
#pragma unroll
      for (int i = 0; i < 8; ++i) {
        int c = (w - 2) * 8 + i;
        int e = c * 16 + ve_sub;
        int lc = vchunk ^ ((e >> 1) & 3);
        gl_lds16(&Vbase[(size_t)e * NSEQ + kt0 + (lc << 3)], &Vsl[c * 512]);
      }
    }
  };

  stage(0, 0);
  __syncthreads();                     // tile 0 resident

  for (int t = 0; t < NT; ++t) {
    const int buf = t & 1;
    const bf16* Ksl = (const bf16*)(smem + buf * 32768);
    const bf16* Vsl = Ksl + 8192;

    // QK^T swapped: each kf feeds both q-halves
    f32x4 s0l = {}, s1l = {}, s0h = {}, s1h = {};
#pragma unroll
    for (int df = 0; df < 4; ++df) {
      const int slot = (((s << 4) + df * 4 + lhi) ^ swz) << 3;
      bf16x8 kf0 = *reinterpret_cast<const bf16x8*>(&Ksl[l15 * 256 + slot]);
      bf16x8 kf1 = *reinterpret_cast<const bf16x8*>(&Ksl[(16 + l15) * 256 + slot]);
      s0l = __builtin_amdgcn_mfma_f32_16x16x32_bf16(kf0, qlo[df], s0l, 0, 0, 0);
      s0h = __builtin_amdgcn_mfma_f32_16x16x32_bf16(kf0, qhi[df], s0h, 0, 0, 0);
      s1l = __builtin_amdgcn_mfma_f32_16x16x32_bf16(kf1, qlo[df], s1l, 0, 0, 0);
      s1h = __builtin_amdgcn_mfma_f32_16x16x32_bf16(kf1, qhi[df], s1h, 0, 0, 0);
    }

    // prefetch next tile: pinned so QK^T starts at barrier-exit; staging issue
    // overlaps the exp2 chain below.
    __builtin_amdgcn_sched_barrier(0);
    if (t + 1 < NT) stage(buf ^ 1, t + 1);
    __builtin_amdgcn_sched_barrier(0);

    // max-free softmax: P = 2^S for both q-halves
    bf16 pbl[8], pbh[8];
    float r0 = 0.f, r1 = 0.f;
#pragma unroll
    for (int r = 0; r < 4; ++r) {
      float e0 = __builtin_amdgcn_exp2f(s0l[r]);
      float e1 = __builtin_amdgcn_exp2f(s1l[r]);
      r0 += e0 + e1;
      pbl[r] = (bf16)e0;
      pbl[4 + r] = (bf16)e1;
      float e2 = __builtin_amdgcn_exp2f(s0h[r]);
      float e3 = __builtin_amdgcn_exp2f(s1h[r]);
      r1 += e2 + e3;
      pbh[r] = (bf16)e2;
      pbh[4 + r] = (bf16)e3;
    }
    ll0 += r0;
    ll1 += r1;
    bf16x8 pal = *reinterpret_cast<const bf16x8*>(pbl);
    bf16x8 pah = *reinterpret_cast<const bf16x8*>(pbh);

    __builtin_amdgcn_s_setprio(1);
#pragma unroll
    for (int eb = 0; eb < 16; ++eb) {
      bf16x8 vf = *reinterpret_cast<const bf16x8*>(&Vsl[(eb * 16 + l15) * 32 + voff]);
      olo[eb] = __builtin_amdgcn_mfma_f32_16x16x32_bf16(pal, vf, olo[eb], 0, 0, 0);
      ohi[eb] = __builtin_amdgcn_mfma_f32_16x16x32_bf16(pah, vf, ohi[eb], 0, 0, 0);
    }
    __builtin_amdgcn_s_setprio(0);

    __syncthreads();                   // drains next-tile loads; frees buf for overwrite
  }

  // epilogue: reduce l per half, cross-wave stream combine (bf16 Z) + RMS rinv + store
  ll0 += __shfl_xor(ll0, 16, 64);
  ll0 += __shfl_xor(ll0, 32, 64);
  ll1 += __shfl_xor(ll1, 16, 64);
  ll1 += __shfl_xor(ll1, 32, 64);
  float L0[4], L1[4];
#pragma unroll
  for (int r = 0; r < 4; ++r) {
    L0[r] = __shfl(ll0, 4 * lhi + r, 64);
    L1[r] = __shfl(ll1, 4 * lhi + r, 64);
  }

  bf16* Zg = Zb + g * 8192;            // [32 rows][256 e] bf16
  if (s) {
#pragma unroll
    for (int r = 0; r < 4; ++r) {
      float i2l = lam / L0[r];
      float i2h = lam / L1[r];
#pragma unroll
      for (int eb = 0; eb < 16; ++eb) {
        Zg[(4 * lhi + r) * 256 + eb * 16 + l15] = (bf16)(olo[eb][r] * i2l);
        Zg[(16 + 4 * lhi + r) * 256 + eb * 16 + l15] = (bf16)(ohi[eb][r] * i2h);
      }
    }
  }
  __syncthreads();
  if (!s) {
#pragma unroll
    for (int half = 0; half < 2; ++half) {
      const f32x4* oh = half ? ohi : olo;
      const float* Lh = half ? L1 : L0;
#pragma unroll
      for (int r = 0; r < 4; ++r) {
        float i1 = 1.0f / Lh[r];
        float vals[16];
        float ssq = 0.f;
#pragma unroll
        for (int eb = 0; eb < 16; ++eb) {
          float v = oh[eb][r] * i1 -
                    (float)Zg[(half * 16 + 4 * lhi + r) * 256 + eb * 16 + l15];
          vals[eb] = v;
          ssq += v * v;
        }
#pragma unroll
        for (int off = 1; off < 16; off <<= 1) ssq += __shfl_xor(ssq, off, 64);
        float rinv = rsqrtf(ssq * (1.0f / 256.0f) + RMS_EPS);
        const int q = q0 + g * 32 + half * 16 + 4 * lhi + r;
        const size_t ob = ((size_t)b * NSEQ + q) * E + (size_t)h * 256;
#pragma unroll
        for (int eb = 0; eb < 16; ++eb) {
          int e = eb * 16 + l15;
          Ob[ob + e] = (bf16)(vals[eb] * rinv);
        }
      }
    }
  }
}

// ---------------------------------------------------------------- launch
extern "C" void kernel_launch(void* const* d_in, const int* in_sizes, int n_in,
                              void* d_out, int out_size, void* d_ws, size_t ws_size,
                              hipStream_t stream) {
  const float* X   = (const float*)d_in[0];
  const float* Wq  = (const float*)d_in[1];
  const float* Wk  = (const float*)d_in[2];
  const float* Wv  = (const float*)d_in[3];
  const float* Wo  = (const float*)d_in[4];
  const float* lq1 = (const float*)d_in[5];
  const float* lk1 = (const float*)d_in[6];
  const float* lq2 = (const float*)d_in[7];
  const float* lk2 = (const float*)d_in[8];
  const float* rs  = (const float*)d_in[9];
  float* out = (float*)d_out;

  constexpr size_t B = 2, NSEQ = 2048, D = 1024, E = 2048;
  constexpr size_t M = B * NSEQ;  // 4096

  char* ws = (char*)d_ws;
  bf16* Xb  = (bf16*)ws;                 // M*D
  bf16* Wqb = Xb + M * D;                // E*D  (Wqb/Wkb/Wvb contiguous -> [6144][1024])
  bf16* Wkb = Wqb + E * D;
  bf16* Wvb = Wkb + E * D;
  bf16* Wob = Wvb + E * D;               // D*E (pre-scaled by rs*osc)
  bf16* Qb  = Wob + D * E;               // M*E  (Qb/Kb/Vtb contiguous for fused epilogue)
  bf16* Kb  = Qb + M * E;
  bf16* Vtb = Kb + M * E;                // M*E, layout [b,h,e,perm(n)]
  bf16* Ob  = Vtb + M * E;               // M*E

  fused_cast<<<2048, 256, 0, stream>>>(X, Wq, Wk, Wv, Wo, rs, Xb);

  gemm_bt<3, 128><<<dim3(M / 128, 6144 / 128), 256, 0, stream>>>(
      Xb, Wqb, Qb, (int)M, 6144, (int)D);

  diff_attn<<<dim3(512), 256, 0, stream>>>(Qb, Kb, Vtb, lq1, lk1, lq2, lk2, Ob);

  gemm_bt<1, 128><<<dim3(M / 128, D / 128), 256, 0, stream>>>(Ob, Wob, out, (int)M, (int)D, (int)E);
}